// Round 8
// baseline (108.695 us; speedup 1.0000x reference)
//
#include <hip/hip_runtime.h>

#define N_NODES 100000
#define N_EDGES 1250000
#define IN_CH 64
#define HID 128
#define OUT_CH 2
#define NUM_GRAPHS 128

#define PSHIFT 7
#define PSIZE 128                               // nodes per partition
#define NPART ((N_NODES + PSIZE - 1) / PSIZE)   // 782
#define SCANW 1024
#define MAXE 2048  // edges/partition: mean 1600, sigma 40 -> 11-sigma safe
#define TILE 4096  // edges per part_k block

typedef _Float16 half2v __attribute__((ext_vector_type(2)));
typedef _Float16 half8 __attribute__((ext_vector_type(8)));
typedef float f32x4 __attribute__((ext_vector_type(4)));

#define HB 64                                     // histogram blocks
#define XCAST_BLOCKS (N_NODES * IN_CH / 4 / 512)  // 3125 (2 float4 per thread)
#define WPREP_BLOCKS 64

// ---------------------------------------------------------------------------
// K1 prep: [0,HB) dst-histogram -> per-block slice (no global atomics, no
// pre-zero), then x->f16 cast, then weight prep.
// ---------------------------------------------------------------------------
__global__ __launch_bounds__(256) void prep_k(const float* __restrict__ x,
                                              const float* __restrict__ W_l,
                                              const float* __restrict__ W_r,
                                              const int* __restrict__ ei,
                                              unsigned short* __restrict__ xh,
                                              unsigned short* __restrict__ Wc,
                                              int* __restrict__ ghist) {
    const int b = (int)blockIdx.x;
    const int tid = (int)threadIdx.x;
    if (b < HB) {
        __shared__ int lh[SCANW];
        for (int i = tid; i < SCANW; i += 256) lh[i] = 0;
        __syncthreads();
        for (int e = b * 256 + tid; e < N_EDGES; e += HB * 256)
            atomicAdd(&lh[ei[N_EDGES + e] >> PSHIFT], 1);
        __syncthreads();
        for (int i = tid; i < SCANW; i += 256) ghist[b * SCANW + i] = lh[i];
        return;
    }
    const int b2 = b - HB;
    if (b2 < XCAST_BLOCKS) {
        const int i0 = b2 * 512 + tid;
#pragma unroll
        for (int t = 0; t < 2; ++t) {
            const int i = i0 + t * 256;
            const float4 v = reinterpret_cast<const float4*>(x)[i];
            half2v a, c;
            a[0] = (_Float16)v.x; a[1] = (_Float16)v.y;
            c[0] = (_Float16)v.z; c[1] = (_Float16)v.w;
            uint2 u;
            u.x = __builtin_bit_cast(unsigned, a);
            u.y = __builtin_bit_cast(unsigned, c);
            reinterpret_cast<uint2*>(xh)[i] = u;
        }
        return;
    }
    const int i = (b2 - XCAST_BLOCKS) * 256 + tid;
    if (i < HID * 2 * IN_CH) {
        const int o = i >> 7;
        const int k = i & 127;
        const float v = (k < IN_CH) ? W_l[o * IN_CH + k] : W_r[o * IN_CH + (k - IN_CH)];
        const _Float16 h = (_Float16)v;
        Wc[i] = __builtin_bit_cast(unsigned short, h);
    }
}

// ---------------------------------------------------------------------------
// K2 scan: reduce 64 hist slices, 1024-wide exclusive prefix (2 elems/thread)
// -> off[] + gcursor[]; also zeroes gmax.
// ---------------------------------------------------------------------------
__global__ __launch_bounds__(512) void scan_k(const int* __restrict__ ghist,
                                              int* __restrict__ off,
                                              int* __restrict__ gcursor,
                                              unsigned int* __restrict__ gmax) {
    __shared__ int sb[2][SCANW];
    const int t = (int)threadIdx.x;
    const int i0 = t, i1 = t + 512;
    int v0 = 0, v1 = 0;
#pragma unroll 8
    for (int b = 0; b < HB; ++b) {
        v0 += ghist[b * SCANW + i0];
        v1 += ghist[b * SCANW + i1];
    }
    if (i1 >= NPART) v1 = 0;  // i0 < 512 < NPART always valid
    sb[0][i0] = v0;
    sb[0][i1] = v1;
    __syncthreads();
    int pb = 0;
    for (int o = 1; o < SCANW; o <<= 1) {
        sb[pb ^ 1][i0] = sb[pb][i0] + ((i0 >= o) ? sb[pb][i0 - o] : 0);
        sb[pb ^ 1][i1] = sb[pb][i1] + ((i1 >= o) ? sb[pb][i1 - o] : 0);
        pb ^= 1;
        __syncthreads();
    }
    off[i0] = sb[pb][i0] - v0;
    gcursor[i0] = sb[pb][i0] - v0;
    off[i1] = sb[pb][i1] - v1;
    gcursor[i1] = sb[pb][i1] - v1;
#pragma unroll
    for (int i = 0; i < (NUM_GRAPHS * HID) / 512; ++i) gmax[i * 512 + t] = 0u;
}

// ---------------------------------------------------------------------------
// K3 part: counting-sort edges into partition buffers, packed u32 per edge
// (src 17b | local-dst 7b << 17). Per-edge ops LDS-only; one global atomic
// per (block,bin); contiguous-run writes.
// ---------------------------------------------------------------------------
__global__ __launch_bounds__(512) void part_k(const int* __restrict__ ei,
                                              int* __restrict__ gcursor,
                                              unsigned* __restrict__ edgesP) {
    __shared__ int lhist[NPART];
    __shared__ int lpre[NPART];
    __shared__ int gbase[NPART];
    __shared__ unsigned stage[TILE];        // 16KB
    __shared__ unsigned short sbin[TILE];   // 8KB
    __shared__ int sb[2][SCANW];            // 8KB

    const int tid = (int)threadIdx.x;
    const int e0 = (int)blockIdx.x * TILE;
    const int nv = min(TILE, N_EDGES - e0);

    for (int i = tid; i < NPART; i += 512) lhist[i] = 0;
    __syncthreads();

    int esrc[8], emeta[8];
#pragma unroll
    for (int k = 0; k < 8; ++k) {
        const int e = e0 + k * 512 + tid;
        emeta[k] = -1;
        if (e < N_EDGES) {
            esrc[k] = ei[e];
            const int dst = ei[N_EDGES + e];
            const int bin = dst >> PSHIFT;       // 10 bits
            const int dl = dst & (PSIZE - 1);    // 7 bits
            const int rank = atomicAdd(&lhist[bin], 1);  // < 4096: 12 bits
            emeta[k] = bin | (dl << 10) | (rank << 17);
        }
    }
    __syncthreads();

    {
        const int i0 = tid, i1 = tid + 512;
        sb[0][i0] = (i0 < NPART) ? lhist[i0] : 0;
        sb[0][i1] = (i1 < NPART) ? lhist[i1] : 0;
        __syncthreads();
        int pb = 0;
        for (int o = 1; o < SCANW; o <<= 1) {
            sb[pb ^ 1][i0] = sb[pb][i0] + ((i0 >= o) ? sb[pb][i0 - o] : 0);
            sb[pb ^ 1][i1] = sb[pb][i1] + ((i1 >= o) ? sb[pb][i1 - o] : 0);
            pb ^= 1;
            __syncthreads();
        }
        if (i0 < NPART) lpre[i0] = sb[pb][i0] - lhist[i0];
        if (i1 < NPART) lpre[i1] = sb[pb][i1] - lhist[i1];
    }
    for (int i = tid; i < NPART; i += 512)
        gbase[i] = lhist[i] ? atomicAdd(&gcursor[i], lhist[i]) : 0;
    __syncthreads();

#pragma unroll
    for (int k = 0; k < 8; ++k) {
        if (emeta[k] >= 0) {
            const int bin = emeta[k] & 1023;
            const int dl = (emeta[k] >> 10) & 127;
            const int rank = emeta[k] >> 17;
            const int pos = lpre[bin] + rank;
            stage[pos] = (unsigned)esrc[k] | ((unsigned)dl << 17);
            sbin[pos] = (unsigned short)bin;
        }
    }
    __syncthreads();

    for (int i = tid; i < nv; i += 512) {
        const int b = sbin[i];
        edgesP[gbase[b] + (i - lpre[b])] = stage[i];
    }
}

// ---------------------------------------------------------------------------
// K4 fused: per 128-node partition: build per-dst CSR in LDS, gather-mean
// (4 threads/node, independent 16B loads), write mean f16 straight into the
// MFMA feature tile (LDS, swizzled; union'd with the CSR region), stage x
// rows, then MFMA GEMM + relu + per-graph max pool. No meanh round-trip.
// ---------------------------------------------------------------------------
__device__ __forceinline__ void acc8(float* a, uint4 v) {
    const half2v h0 = __builtin_bit_cast(half2v, v.x);
    const half2v h1 = __builtin_bit_cast(half2v, v.y);
    const half2v h2 = __builtin_bit_cast(half2v, v.z);
    const half2v h3 = __builtin_bit_cast(half2v, v.w);
    a[0] += (float)h0[0]; a[1] += (float)h0[1];
    a[2] += (float)h1[0]; a[3] += (float)h1[1];
    a[4] += (float)h2[0]; a[5] += (float)h2[1];
    a[6] += (float)h3[0]; a[7] += (float)h3[1];
}

__device__ __forceinline__ unsigned pkh2(float a, float b) {
    half2v h;
    h[0] = (_Float16)a;
    h[1] = (_Float16)b;
    return __builtin_bit_cast(unsigned, h);
}

__global__ __launch_bounds__(512, 4) void fused_k(const unsigned short* __restrict__ xh,
                                                  const int* __restrict__ off,
                                                  const unsigned* __restrict__ edgesP,
                                                  const unsigned short* __restrict__ Wc,
                                                  const float* __restrict__ b_l,
                                                  const int* __restrict__ batch,
                                                  unsigned int* __restrict__ gmax) {
    // 32KB union: CSR scratch (14KB) during mean phase, feature tile after.
    __shared__ __align__(16) unsigned char uni[PSIZE * 16 * 16];
    __shared__ uint4 wt[HID * 16];       // 32KB weights [out][16 chunks, swz]
    __shared__ unsigned lmax[4 * HID];   // 2KB
    __shared__ int bt[PSIZE];

    uint4* fe = reinterpret_cast<uint4*>(uni);
    int* ss = reinterpret_cast<int*>(uni);                         // [MAXE] 8KB
    unsigned char* dl8 = uni + MAXE * 4;                           // 2KB
    unsigned char* rk8 = uni + MAXE * 5;                           // 2KB
    int* histL = reinterpret_cast<int*>(uni + MAXE * 6);           // 512B
    int* rowp = reinterpret_cast<int*>(uni + MAXE * 6 + 512);      // 512B

    const int tid = (int)threadIdx.x;
    const int p = (int)blockIdx.x;
    const int nb = p * PSIZE;
    const int nvalid = min(PSIZE, N_NODES - nb);
    const int e0 = off[p];
    const int m = min(off[p + 1] - e0, MAXE);

    // weights (independent region)
#pragma unroll
    for (int t = 0; t < 4; ++t) {
        const int id = tid + t * 512;
        const int row = id >> 4, c = id & 15;
        wt[row * 16 + (c ^ (row & 7))] = reinterpret_cast<const uint4*>(Wc)[row * 16 + c];
    }
    if (tid < PSIZE) {
        histL[tid] = 0;
        bt[tid] = (nb + tid < N_NODES) ? batch[nb + tid] : -1;
    }
    lmax[tid] = 0u;  // 4*HID == 512
    __syncthreads();

    // CSR pass 1: local-dst + rank
    for (int i = tid; i < m; i += 512) {
        const unsigned pr = edgesP[e0 + i];
        const int d = (int)((pr >> 17) & 127u);
        dl8[i] = (unsigned char)d;
        rk8[i] = (unsigned char)atomicAdd(&histL[d], 1);
    }
    __syncthreads();

    // 128-entry exclusive scan in wave 0 (2 elems/lane)
    if (tid < 64) {
        const int vlo = histL[tid], vhi = histL[tid + 64];
        int slo = vlo, shi = vhi;
#pragma unroll
        for (int o = 1; o < 64; o <<= 1) {
            const int t0 = __shfl_up(slo, o, 64);
            const int t1 = __shfl_up(shi, o, 64);
            if (tid >= o) { slo += t0; shi += t1; }
        }
        const int tot = __shfl(slo, 63, 64);
        rowp[tid] = slo - vlo;
        rowp[tid + 64] = tot + shi - vhi;
    }
    __syncthreads();

    // CSR pass 2: scatter srcs into per-dst runs (LDS)
    for (int i = tid; i < m; i += 512)
        ss[rowp[dl8[i]] + rk8[i]] = (int)(edgesP[e0 + i] & 0x1FFFFu);
    __syncthreads();

    // gather-mean: 4 threads per node, each owns 16 channels (2 x 16B)
    const int owner = tid >> 2;
    const int qd = tid & 2 ? (tid & 3) : (tid & 3);  // = tid & 3
    const int node = nb + owner;
    float acc[16];
#pragma unroll
    for (int i = 0; i < 16; ++i) acc[i] = 0.f;
    int deg = 0, base = 0;
    if (node < N_NODES) { deg = histL[owner]; base = rowp[owner]; }

    int j = 0;
    for (; j + 2 <= deg; j += 2) {
        const int s0 = ss[base + j];
        const int s1 = ss[base + j + 1];
        const uint4* r0 = reinterpret_cast<const uint4*>(xh + (size_t)s0 * IN_CH + (tid & 3) * 16);
        const uint4* r1 = reinterpret_cast<const uint4*>(xh + (size_t)s1 * IN_CH + (tid & 3) * 16);
        const uint4 a0 = r0[0], a1 = r0[1];
        const uint4 b0 = r1[0], b1 = r1[1];
        acc8(acc + 0, a0); acc8(acc + 8, a1);
        acc8(acc + 0, b0); acc8(acc + 8, b1);
    }
    if (j < deg) {
        const int s0 = ss[base + j];
        const uint4* r0 = reinterpret_cast<const uint4*>(xh + (size_t)s0 * IN_CH + (tid & 3) * 16);
        const uint4 a0 = r0[0], a1 = r0[1];
        acc8(acc + 0, a0); acc8(acc + 8, a1);
    }

    const float rcp = 1.0f / fmaxf((float)deg, 1.0f);
    uint4 pk0, pk1;
    pk0.x = pkh2(acc[0] * rcp, acc[1] * rcp);
    pk0.y = pkh2(acc[2] * rcp, acc[3] * rcp);
    pk0.z = pkh2(acc[4] * rcp, acc[5] * rcp);
    pk0.w = pkh2(acc[6] * rcp, acc[7] * rcp);
    pk1.x = pkh2(acc[8] * rcp, acc[9] * rcp);
    pk1.y = pkh2(acc[10] * rcp, acc[11] * rcp);
    pk1.z = pkh2(acc[12] * rcp, acc[13] * rcp);
    pk1.w = pkh2(acc[14] * rcp, acc[15] * rcp);

    __syncthreads();  // CSR region dead; safe to overwrite as fe

    if (node < N_NODES) {
        const int c0 = (tid & 3) * 2;
        fe[owner * 16 + (c0 ^ (owner & 7))] = pk0;
        fe[owner * 16 + ((c0 + 1) ^ (owner & 7))] = pk1;
    }
    // stage x rows into chunks 8..15
#pragma unroll
    for (int t = 0; t < 2; ++t) {
        const int id = tid + t * 512;
        const int row = id >> 3, c8 = id & 7;
        const int n = nb + row;
        uint4 v = make_uint4(0u, 0u, 0u, 0u);
        if (n < N_NODES) v = reinterpret_cast<const uint4*>(xh)[(size_t)n * 8 + c8];
        fe[row * 16 + ((8 + c8) ^ (row & 7))] = v;
    }
    __syncthreads();

    // MFMA GEMM 128x128, K=128
    const int lane = tid & 63;
    const int w = tid >> 6;
    const int l15 = lane & 15, q = lane >> 4;

    f32x4 gacc[8];
#pragma unroll
    for (int nt = 0; nt < 8; ++nt) gacc[nt] = (f32x4){0.f, 0.f, 0.f, 0.f};

    const int arow = w * 16 + l15;
#pragma unroll
    for (int kb = 0; kb < 4; ++kb) {
        const int ac = kb * 4 + q;
        const half8 a = __builtin_bit_cast(half8, fe[arow * 16 + (ac ^ (arow & 7))]);
#pragma unroll
        for (int nt = 0; nt < 8; ++nt) {
            const int nrow = nt * 16 + l15;
            const half8 b = __builtin_bit_cast(half8, wt[nrow * 16 + (ac ^ (nrow & 7))]);
            gacc[nt] = __builtin_amdgcn_mfma_f32_16x16x32_f16(a, b, gacc[nt], 0, 0, 0);
        }
    }

    float bias[8];
#pragma unroll
    for (int nt = 0; nt < 8; ++nt) bias[nt] = b_l[nt * 16 + l15];

    // segmented max over this lane's 4 node rows (batch sorted)
    const int gbase = bt[0];
    const int rowb = w * 16 + q * 4;
    int curg = -1;
    float rmax[8];
#pragma unroll
    for (int nt = 0; nt < 8; ++nt) rmax[nt] = 0.f;

#pragma unroll
    for (int reg = 0; reg < 4; ++reg) {
        const int g = bt[rowb + reg];
        if (g >= 0) {
            float h[8];
#pragma unroll
            for (int nt = 0; nt < 8; ++nt) h[nt] = fmaxf(gacc[nt][reg] + bias[nt], 0.f);
            if (g != curg) {
                if (curg >= 0) {
                    const int slot = curg - gbase;
                    if (slot < 4) {
#pragma unroll
                        for (int nt = 0; nt < 8; ++nt)
                            atomicMax(&lmax[slot * HID + nt * 16 + l15], __float_as_uint(rmax[nt]));
                    } else {
#pragma unroll
                        for (int nt = 0; nt < 8; ++nt)
                            atomicMax(&gmax[(size_t)curg * HID + nt * 16 + l15], __float_as_uint(rmax[nt]));
                    }
                }
                curg = g;
#pragma unroll
                for (int nt = 0; nt < 8; ++nt) rmax[nt] = h[nt];
            } else {
#pragma unroll
                for (int nt = 0; nt < 8; ++nt) rmax[nt] = fmaxf(rmax[nt], h[nt]);
            }
        }
    }
    if (curg >= 0) {
        const int slot = curg - gbase;
        if (slot < 4) {
#pragma unroll
            for (int nt = 0; nt < 8; ++nt)
                atomicMax(&lmax[slot * HID + nt * 16 + l15], __float_as_uint(rmax[nt]));
        } else {
#pragma unroll
            for (int nt = 0; nt < 8; ++nt)
                atomicMax(&gmax[(size_t)curg * HID + nt * 16 + l15], __float_as_uint(rmax[nt]));
        }
    }
    __syncthreads();

    int span = bt[nvalid - 1] - gbase + 1;
    if (span > 4) span = 4;
    if (tid < span * HID) {
        const unsigned v = lmax[tid];
        if (v) atomicMax(&gmax[(size_t)(gbase + (tid >> 7)) * HID + (tid & 127)], v);
    }
}

// ---------------------------------------------------------------------------
// K5: head. out[g][oc] = gmax[g].W_lin[oc] + b_lin[oc]
// ---------------------------------------------------------------------------
__global__ __launch_bounds__(256) void head_k(const unsigned int* __restrict__ gmax_u,
                                              const float* __restrict__ W_lin,
                                              const float* __restrict__ b_lin,
                                              float* __restrict__ out) {
    const int t = (int)threadIdx.x;
    const int g = t >> 1;
    const int oc = t & 1;
    const float* gm = (const float*)gmax_u;
    float acc = b_lin[oc];
#pragma unroll 4
    for (int k = 0; k < HID; ++k) acc += gm[(size_t)g * HID + k] * W_lin[oc * HID + k];
    out[(size_t)g * OUT_CH + oc] = acc;
}

extern "C" void kernel_launch(void* const* d_in, const int* in_sizes, int n_in,
                              void* d_out, int out_size, void* d_ws, size_t ws_size,
                              hipStream_t stream) {
    const float* x = (const float*)d_in[0];
    const float* W_l = (const float*)d_in[1];
    const float* b_l = (const float*)d_in[2];
    const float* W_r = (const float*)d_in[3];
    const float* W_lin = (const float*)d_in[4];
    const float* b_lin = (const float*)d_in[5];
    const int* ei = (const int*)d_in[6];
    const int* batch = (const int*)d_in[7];
    float* out = (float*)d_out;

    char* ws = (char*)d_ws;
    size_t o = 0;
    int* ghist = (int*)(ws + o); o += (size_t)HB * SCANW * 4;                          // 256KB
    unsigned int* gmax = (unsigned int*)(ws + o); o += (size_t)NUM_GRAPHS * HID * 4;   // 64KB
    int* off = (int*)(ws + o); o += SCANW * 4;
    int* gcursor = (int*)(ws + o); o += SCANW * 4;
    unsigned* edgesP = (unsigned*)(ws + o); o += (size_t)N_EDGES * 4;                  // 5MB
    unsigned short* xh = (unsigned short*)(ws + o); o += (size_t)N_NODES * IN_CH * 2;  // 12.8MB
    unsigned short* Wc = (unsigned short*)(ws + o); o += (size_t)HID * 2 * IN_CH * 2;  // 32KB

    // no memsets: ghist slice-overwritten; gmax/off/gcursor written by scan_k;
    // edgesP fully overwritten by part_k.

    prep_k<<<HB + XCAST_BLOCKS + WPREP_BLOCKS, 256, 0, stream>>>(x, W_l, W_r, ei, xh, Wc, ghist);
    scan_k<<<1, 512, 0, stream>>>(ghist, off, gcursor, gmax);
    part_k<<<(N_EDGES + TILE - 1) / TILE, 512, 0, stream>>>(ei, gcursor, edgesP);
    fused_k<<<NPART, 512, 0, stream>>>(xh, off, edgesP, Wc, b_l, batch, gmax);
    head_k<<<1, 256, 0, stream>>>(gmax, W_lin, b_lin, out);
}